// Round 8
// baseline (696.558 us; speedup 1.0000x reference)
//
#include <hip/hip_runtime.h>

// ---------------------------------------------------------------------------
// SAGE_Re GNN forward, R12.
// - GEMM: BM=256 (tile 256xBN, 4*BN threads, per-wave 64x64). Halves the
//   B-panel re-stage traffic (the dominant GEMM request-path cost:
//   (M/BM)*K*N*2 bytes). 3-stage dist-3 counted-vmcnt pipeline kept.
// - GEMM: CORRECTED LDS swizzle: seg ^= (row>>1)&3 (old (row&3) version left
//   lanes {0,4,8,12} colliding -> the invariant 3.2M bank conflicts).
// - agg: R9/R11 unconditional UNR=4 gathers (request-path-bound; proven
//   invariant to instruction count).
// - L4 commuted (R10); fp16 + swapped-operand C^T epilogue (R9).
// - CSR: 3-phase multi-block scan (R5).
// ---------------------------------------------------------------------------

typedef _Float16 __attribute__((ext_vector_type(8))) f16x8;
typedef _Float16 __attribute__((ext_vector_type(2))) f16x2;
typedef __attribute__((ext_vector_type(4))) float f32x4;

__device__ __forceinline__ unsigned short f2h(float f) {
    union { _Float16 h; unsigned short u; } v; v.h = (_Float16)f; return v.u;
}
__device__ __forceinline__ float h2f(unsigned short u) {
    union { unsigned short u; _Float16 h; } v; v.u = u; return (float)v.h;
}

// ---------------- CSR build ----------------

__global__ __launch_bounds__(256) void zero_int_kernel(int* __restrict__ p, int n)
{
    int i = blockIdx.x * 256 + threadIdx.x;
    if (i < n) p[i] = 0;
}

__global__ __launch_bounds__(256) void count_deg_kernel(
    const int* __restrict__ row, int* __restrict__ deg, int E)
{
    int e = blockIdx.x * 256 + threadIdx.x;
    if (e < E) atomicAdd(&deg[row[e]], 1);
}

__global__ __launch_bounds__(1024) void scan_p1_kernel(
    const int* __restrict__ deg, int* __restrict__ rp,
    int* __restrict__ bsum, int n)
{
    __shared__ int wsum[16];
    int t = threadIdx.x, lane = t & 63, w = t >> 6;
    int base = blockIdx.x * 2048;
    int carry = 0;
    #pragma unroll
    for (int half = 0; half < 2; ++half) {
        int i = base + half * 1024 + t;
        int xv = (i < n) ? deg[i] : 0;
        int s = xv;
        #pragma unroll
        for (int off = 1; off < 64; off <<= 1) {
            int v = __shfl_up(s, off, 64);
            if (lane >= off) s += v;
        }
        if (lane == 63) wsum[w] = s;
        __syncthreads();
        if (w == 0 && lane < 16) {
            int ws = wsum[lane];
            #pragma unroll
            for (int off = 1; off < 16; off <<= 1) {
                int v = __shfl_up(ws, off, 64);
                if (lane >= off) ws += v;
            }
            wsum[lane] = ws;
        }
        __syncthreads();
        int wo = (w == 0) ? 0 : wsum[w - 1];
        if (i < n) rp[i + 1] = carry + wo + s;
        carry += wsum[15];
        if (half == 0) __syncthreads();
    }
    if (t == 0) bsum[blockIdx.x] = carry;
}

__global__ __launch_bounds__(64) void scan_p2_kernel(int* __restrict__ bsum, int B)
{
    int lane = threadIdx.x;
    int v = (lane < B) ? bsum[lane] : 0;
    int s = v;
    #pragma unroll
    for (int off = 1; off < 64; off <<= 1) {
        int u = __shfl_up(s, off, 64);
        if (lane >= off) s += u;
    }
    if (lane < B) bsum[lane] = s - v;
}

__global__ __launch_bounds__(1024) void scan_p3_kernel(
    const int* __restrict__ deg, int* __restrict__ rp,
    int* __restrict__ cursor, const int* __restrict__ bsum,
    float* __restrict__ dinv, float* __restrict__ cinv, int n)
{
    int boff = bsum[blockIdx.x];
    int base = blockIdx.x * 2048;
    #pragma unroll
    for (int half = 0; half < 2; ++half) {
        int i = base + half * 1024 + threadIdx.x;
        if (i < n) {
            int d = deg[i];
            int incl = rp[i + 1] + boff;
            rp[i + 1] = incl;
            cursor[i] = incl - d;
            float df = (float)d;
            dinv[i] = (d > 0) ? rsqrtf(df) : 0.0f;
            cinv[i] = 1.0f / fmaxf(df, 1.0f);
        }
    }
    if (blockIdx.x == 0 && threadIdx.x == 0) rp[0] = 0;
}

__global__ __launch_bounds__(256) void fill_csr_kernel(
    const int* __restrict__ row, const int* __restrict__ col,
    int* __restrict__ cursor, int* __restrict__ colS, int E)
{
    int e = blockIdx.x * 256 + threadIdx.x;
    if (e < E) {
        int p = atomicAdd(&cursor[row[e]], 1);
        colS[p] = col[e];
    }
}

// ---------------- prep ----------------

__global__ __launch_bounds__(256) void f32_to_f16_kernel(
    const float* __restrict__ src, unsigned short* __restrict__ dst, int n4)
{
    int i = blockIdx.x * 256 + threadIdx.x;
    if (i >= n4) return;
    float4 v = ((const float4*)src)[i];
    ushort4 o;
    o.x = f2h(v.x); o.y = f2h(v.y); o.z = f2h(v.z); o.w = f2h(v.w);
    ((ushort4*)dst)[i] = o;
}

__global__ __launch_bounds__(256) void prep_w_kernel(
    const float* __restrict__ S1, int K1,
    const float* __restrict__ S2, int K2,
    int Nout, int Npad, unsigned short* __restrict__ dst)
{
    int Ktot = K1 + K2;
    int idx = blockIdx.x * 256 + threadIdx.x;
    if (idx >= Npad * Ktot) return;
    int n = idx / Ktot, k = idx - n * Ktot;
    float v = 0.0f;
    if (n < Nout)
        v = (k < K1) ? S1[(size_t)k * Nout + n] : S2[(size_t)(k - K1) * Nout + n];
    dst[idx] = f2h(v);
}

// L4 weight prep: dst is 256 rows (n) x 256 cols (k):
//   n<112 -> W4[:,n] ; 112<=n<224 -> R4[:,n-112] ; else 0.
__global__ __launch_bounds__(256) void prep_w2_kernel(
    const float* __restrict__ W4, const float* __restrict__ R4,
    unsigned short* __restrict__ dst)
{
    int idx = blockIdx.x * 256 + threadIdx.x;   // 256*256 total
    int nrow = idx >> 8, k = idx & 255;
    float v = 0.0f;
    if (nrow < 112)      v = W4[(size_t)k * 112 + nrow];
    else if (nrow < 224) v = R4[(size_t)k * 112 + (nrow - 112)];
    dst[idx] = f2h(v);
}

__global__ __launch_bounds__(256) void prep_biasP_kernel(
    const float* __restrict__ b4, float* __restrict__ biasP)
{
    int i = threadIdx.x;   // 256
    biasP[i] = (i >= 112 && i < 224) ? b4[i - 112] : 0.0f;
}

// ---------------- aggregation: wave per node, packed-f16 accumulation ------
// OUT_MODE 0: out f16 (acc * nscale).   OUT_MODE 1: fout (f32, width 112)
//   += nscale * acc   (RMW of the GEMM-produced U term).

template <int C, bool HAS_ES, int OUT_MODE>
__global__ __launch_bounds__(256) void agg_f16_kernel(
    const unsigned short* __restrict__ h, int ldh,
    const int* __restrict__ rp, const int* __restrict__ cols,
    const float* __restrict__ escale, const float* __restrict__ nscale,
    unsigned short* __restrict__ out, int ldo,
    float* __restrict__ fout, int ldof, int n)
{
    constexpr int LPE = (C == 256) ? 32 : 16;  // lanes per edge
    constexpr int EPG = 64 / LPE;              // edges per group (2 or 4)
    constexpr int UNR = 4;                     // gathers in flight per lane
    int node = blockIdx.x * 4 + (threadIdx.x >> 6);
    if (node >= n) return;
    int lane = threadIdx.x & 63;
    int grp = lane / LPE, sub = lane % LPE;
    const unsigned short* hc = h + sub * 8;

    int s = rp[node], e = rp[node + 1];
    const _Float16 hz = (_Float16)0.0f;
    f16x2 zz = { hz, hz };
    f16x2 acc2[4];
    #pragma unroll
    for (int k = 0; k < 4; ++k) acc2[k] = zz;

    for (int i = s; i < e; i += UNR * EPG) {
        int cc[UNR]; f16x2 ssv[UNR]; uint4 uu[UNR];
        #pragma unroll
        for (int u = 0; u < UNR; ++u) {
            int ii = i + u * EPG + grp;
            bool valid = ii < e;
            int c = valid ? cols[ii] : 0;
            cc[u] = c;
            float sc = valid ? (HAS_ES ? escale[c] : 1.0f) : 0.0f;
            _Float16 sh = (_Float16)sc;
            f16x2 sv = { sh, sh };
            ssv[u] = sv;
        }
        #pragma unroll
        for (int u = 0; u < UNR; ++u)
            uu[u] = *(const uint4*)(hc + (size_t)cc[u] * ldh);
        #pragma unroll
        for (int u = 0; u < UNR; ++u) {
            union { uint4 q; f16x2 hh[4]; } cv; cv.q = uu[u];
            #pragma unroll
            for (int p = 0; p < 4; ++p)
                acc2[p] += cv.hh[p] * ssv[u];       // v_pk_fma_f16
        }
    }

    #pragma unroll
    for (int k = 0; k < 4; ++k) {
        union { f16x2 h2; float f; } a, b;
        a.h2 = acc2[k];
        if (EPG == 4) { b.f = __shfl_xor(a.f, 16, 64); a.h2 = a.h2 + b.h2; }
        b.f = __shfl_xor(a.f, 32, 64); a.h2 = a.h2 + b.h2;
        acc2[k] = a.h2;
    }

    if (OUT_MODE == 0) {
        if (grp == 0) {
            _Float16 nh = (_Float16)nscale[node];
            f16x2 nn = { nh, nh };
            union { uint4 q; f16x2 hh[4]; } o;
            #pragma unroll
            for (int p = 0; p < 4; ++p) o.hh[p] = acc2[p] * nn;
            *(uint4*)(out + (size_t)node * ldo + sub * 8) = o.q;
        }
    } else {
        // fout[node][sub*8 .. +7] += nscale * acc  (cols >= 112 skipped)
        if (grp == 0 && sub < 14) {
            float cs = nscale[node];
            float* U = fout + (size_t)node * ldof + sub * 8;
            float4 u0 = *(float4*)U;
            float4 u1 = *(float4*)(U + 4);
            u0.x += cs * (float)acc2[0][0];
            u0.y += cs * (float)acc2[0][1];
            u0.z += cs * (float)acc2[1][0];
            u0.w += cs * (float)acc2[1][1];
            u1.x += cs * (float)acc2[2][0];
            u1.y += cs * (float)acc2[2][1];
            u1.z += cs * (float)acc2[3][0];
            u1.w += cs * (float)acc2[3][1];
            *(float4*)U = u0;
            *(float4*)(U + 4) = u1;
        }
    }
}

// ---------------- fp16 MFMA GEMM, 256 x BN tile, 3-stage dist-3 pipeline ----
// 4*BN threads (1024 for BN=256 -> 16 waves 4Mx4N; 512 for BN=128 -> 8 waves
// 4Mx2N). Per-wave output 64x64 (acc[4][4]). MFMA operands SWAPPED:
// acc = mfma(B_frag, A_frag) = C^T fragment -> wide epilogue stores.
// Swizzle: LDS[row][sp] = global[row][sp ^ ((row&15)>>1)&3]; store side uses
// src seg (t&3)^((t>>3)&3); read side sp = q ^ ((l16>>1)&3). <=2-way banks.
// EPI: 0 none, 1 relu, 2 residual (res + alpha*v), 3 dual-output L4
//   (n<112 -> f16 T at outb/ldo; n>=112 -> f32 U at outf/ldres).

__device__ __forceinline__ void g2l16(const unsigned short* g, unsigned short* l) {
    __builtin_amdgcn_global_load_lds(
        (const __attribute__((address_space(1))) unsigned int*)g,
        (__attribute__((address_space(3))) unsigned int*)l, 16, 0, 0);
}

template <int BN, int EPI, bool RES_F16, bool WF32, bool WB16>
__global__ __launch_bounds__(4 * BN) void mfma_gemm_kernel(
    const unsigned short* __restrict__ A1, int K1, int lda1,
    const unsigned short* __restrict__ A2, int K2, int lda2,
    const unsigned short* __restrict__ Bt,
    const float* __restrict__ bias,
    const void* __restrict__ res, int ldres,
    const float* __restrict__ alpha_ptr, int alpha_idx,
    float* __restrict__ outf, unsigned short* __restrict__ outb, int ldo,
    int M, int Nout)
{
    constexpr int THREADS = 4 * BN;      // 1024 or 512
    constexpr int AI = (BN == 256) ? 1 : 2;  // A-stage loads per thread
    constexpr int L  = AI + 1;               // total loads per chunk per thread
    constexpr int RPP = THREADS / 4;         // rows staged per pass (256 or 128)
    __shared__ unsigned short As[3][256 * 32];
    __shared__ unsigned short Bs[3][BN * 32];
    int t = threadIdx.x;
    int m0 = blockIdx.x * 256, n0 = blockIdx.y * BN;
    int Ktot = K1 + K2;
    int w = t >> 6, lane = t & 63;
    int wm = w & 3, wn = w >> 2;         // 4 M-waves; 4 or 2 N-waves
    int q = lane >> 4, l16 = lane & 15;

    // store-side swizzle: thread t stages row (t>>2), fetching source 16B-seg
    // (t&3) ^ ((t>>3)&3) so that LDS[row][sp] = global[row][sp ^ ((row&15)>>1)&3].
    int koff = (((t & 3) ^ ((t >> 3) & 3)) * 8);
    int rsub = t >> 2;                   // staged row within pass: 0..RPP-1

    f32x4 acc[4][4];
    #pragma unroll
    for (int i = 0; i < 4; ++i)
        #pragma unroll
        for (int j = 0; j < 4; ++j)
            #pragma unroll
            for (int r = 0; r < 4; ++r) acc[i][j][r] = 0.0f;

    const int KC = Ktot >> 5;

    auto issue = [&](int kc, int p) {
        int k0 = kc * 32;
        const unsigned short* Ap; int lda, kk;
        if (k0 < K1) { Ap = A1; lda = lda1; kk = k0; }
        else         { Ap = A2; lda = lda2; kk = k0 - K1; }
        #pragma unroll
        for (int a = 0; a < AI; ++a) {
            int gm = m0 + a * RPP + rsub; if (gm >= M) gm = M - 1;
            g2l16(Ap + (size_t)gm * lda + kk + koff,
                  &As[p][a * (RPP * 32) + w * 512]);
        }
        {
            int gn = n0 + rsub;                      // < Npad by construction
            g2l16(Bt + (size_t)gn * Ktot + k0 + koff, &Bs[p][w * 512]);
        }
    };

    // read-side swizzle: sp = q ^ ((l16>>1)&3); row&15 == l16 for all frags
    const int cq = (q ^ ((l16 >> 1) & 3)) * 8;
    const int rbA = (wm * 64 + l16) * 32 + cq;
    const int rbB = (wn * 64 + l16) * 32 + cq;

    issue(0, 0);
    if (KC > 1) issue(1, 1);
    if (KC > 2) issue(2, 2);

    int p = 0;
    for (int kc = 0; kc < KC; ++kc) {
        int rem = KC - 1 - kc;   // chunks issued after kc (capped at 2)
        // steady state: chunks kc, kc+1, kc+2 outstanding -> drain kc only.
        if (rem >= 2) {
            if constexpr (L == 3) asm volatile("s_waitcnt vmcnt(6)" ::: "memory");
            else                  asm volatile("s_waitcnt vmcnt(4)" ::: "memory");
        } else if (rem == 1) {
            if constexpr (L == 3) asm volatile("s_waitcnt vmcnt(3)" ::: "memory");
            else                  asm volatile("s_waitcnt vmcnt(2)" ::: "memory");
        } else {
            asm volatile("s_waitcnt vmcnt(0)" ::: "memory");
        }
        __builtin_amdgcn_s_barrier();      // B1: chunk-kc data visible everywhere
        asm volatile("" ::: "memory");

        f16x8 af[4], bfr[4];
        #pragma unroll
        for (int i = 0; i < 4; ++i)
            af[i] = *(const f16x8*)&As[p][rbA + i * 512];
        #pragma unroll
        for (int j = 0; j < 4; ++j)
            bfr[j] = *(const f16x8*)&Bs[p][rbB + j * 512];

        asm volatile("s_waitcnt lgkmcnt(0)" ::: "memory");
        __builtin_amdgcn_s_barrier();      // B2: all waves done reading buf p
        asm volatile("" ::: "memory");
        if (kc + 3 < KC) issue(kc + 3, p); // distance-3 prefetch into freed buf

        __builtin_amdgcn_s_setprio(1);
        #pragma unroll
        for (int i = 0; i < 4; ++i)
            #pragma unroll
            for (int j = 0; j < 4; ++j)
                acc[i][j] = __builtin_amdgcn_mfma_f32_16x16x32_f16(
                    bfr[j], af[i], acc[i][j], 0, 0, 0);   // SWAPPED -> C^T frag
        __builtin_amdgcn_s_setprio(0);

        p = (p == 2) ? 0 : p + 1;
    }

    // Epilogue (swapped layout): lane (q,l16) holds, for tile (i,j),
    // m = m0 + wm*64 + i*16 + l16 (fixed), n = n0 + wn*64 + j*16 + q*4 + r.
    float alpha = 0.0f;
    if (EPI == 2) alpha = alpha_ptr[alpha_idx];
    #pragma unroll
    for (int i = 0; i < 4; ++i) {
        int m = m0 + wm * 64 + i * 16 + l16;
        if (m >= M) continue;
        #pragma unroll
        for (int j = 0; j < 4; ++j) {
            int nb = n0 + wn * 64 + j * 16 + q * 4;
            if (nb >= Nout) continue;
            float4 bv = *(const float4*)&bias[nb];
            float v0 = acc[i][j][0] + bv.x;
            float v1 = acc[i][j][1] + bv.y;
            float v2 = acc[i][j][2] + bv.z;
            float v3 = acc[i][j][3] + bv.w;
            if (EPI == 3) {
                if (nb < 112) {
                    *(ushort4*)&outb[(size_t)m * ldo + nb] =
                        make_ushort4(f2h(v0), f2h(v1), f2h(v2), f2h(v3));
                } else {
                    *(float4*)&outf[(size_t)m * ldres + (nb - 112)] =
                        make_float4(v0, v1, v2, v3);
                }
                continue;
            }
            if (EPI == 1) {
                v0 = fmaxf(v0, 0.0f); v1 = fmaxf(v1, 0.0f);
                v2 = fmaxf(v2, 0.0f); v3 = fmaxf(v3, 0.0f);
            }
            if (EPI == 2) {
                if (RES_F16) {
                    ushort4 rr = *(const ushort4*)
                        ((const unsigned short*)res + (size_t)m * ldres + nb);
                    v0 = h2f(rr.x) + alpha * v0;
                    v1 = h2f(rr.y) + alpha * v1;
                    v2 = h2f(rr.z) + alpha * v2;
                    v3 = h2f(rr.w) + alpha * v3;
                } else {
                    float4 rr = *(const float4*)
                        ((const float*)res + (size_t)m * ldres + nb);
                    v0 = rr.x + alpha * v0;
                    v1 = rr.y + alpha * v1;
                    v2 = rr.z + alpha * v2;
                    v3 = rr.w + alpha * v3;
                }
            }
            if (WF32) {
                *(float4*)&outf[(size_t)m * ldo + nb] = make_float4(v0, v1, v2, v3);
            }
            if (WB16) {
                *(ushort4*)&outb[(size_t)m * ldo + nb] =
                    make_ushort4(f2h(v0), f2h(v1), f2h(v2), f2h(v3));
            }
        }
    }
}

// ---------------------------------------------------------------------------

extern "C" void kernel_launch(void* const* d_in, const int* in_sizes, int n_in,
                              void* d_out, int out_size, void* d_ws, size_t ws_size,
                              hipStream_t stream)
{
    const float* x      = (const float*)d_in[0];
    const int*   ei     = (const int*)d_in[1];
    const float* alpha  = (const float*)d_in[2];
    const float* W0     = (const float*)d_in[3];
    const float* b0     = (const float*)d_in[4];
    const float* W1     = (const float*)d_in[5];
    const float* R1     = (const float*)d_in[6];
    const float* b1     = (const float*)d_in[7];
    const float* W2     = (const float*)d_in[8];
    const float* R2     = (const float*)d_in[9];
    const float* b2     = (const float*)d_in[10];
    const float* W3     = (const float*)d_in[11];
    const float* b3     = (const float*)d_in[12];
    const float* W4     = (const float*)d_in[13];
    const float* R4     = (const float*)d_in[14];
    const float* b4     = (const float*)d_in[15];

    const int N = in_sizes[0] / 128;
    const int E = in_sizes[1] / 2;
    const int* row = ei;
    const int* col = ei + E;

    size_t off = 0;
    auto alloc = [&](size_t bytes) -> void* {
        void* p = (char*)d_ws + off;
        off += (bytes + 255) & ~(size_t)255;
        return p;
    };
    int*   deg    = (int*)alloc((size_t)N * 4);
    int*   rp     = (int*)alloc((size_t)(N + 1) * 4);
    int*   cursor = (int*)alloc((size_t)N * 4);
    int*   colS   = (int*)alloc((size_t)E * 4);
    int*   bsum   = (int*)alloc((size_t)64 * 4);
    float* dinv   = (float*)alloc((size_t)N * 4);
    float* cinv   = (float*)alloc((size_t)N * 4);
    unsigned short* Wt0 = (unsigned short*)alloc((size_t)128 * 128 * 2);
    unsigned short* Wt1 = (unsigned short*)alloc((size_t)256 * 256 * 2);
    unsigned short* Wt2 = (unsigned short*)alloc((size_t)256 * 512 * 2);
    unsigned short* Wt3 = (unsigned short*)alloc((size_t)256 * 256 * 2);
    unsigned short* Wt4p= (unsigned short*)alloc((size_t)256 * 256 * 2);
    float* biasP  = (float*)alloc((size_t)256 * 4);
    unsigned short* Xb  = (unsigned short*)alloc((size_t)N * 128 * 2);
    unsigned short* Gb  = (unsigned short*)alloc((size_t)N * 256 * 2);
    unsigned short* Pb  = (unsigned short*)alloc((size_t)N * 256 * 2);
    unsigned short* Ab  = (unsigned short*)alloc((size_t)N * 256 * 2);
    unsigned short* Hb  = Xb;  // alias: Xb only read by L0 agg before Hb written
    (void)ws_size;

    // ---- CSR build ----
    const int SB = (N + 2047) / 2048;
    zero_int_kernel<<<(N + 255) / 256, 256, 0, stream>>>(deg, N);
    count_deg_kernel<<<(E + 255) / 256, 256, 0, stream>>>(row, deg, E);
    scan_p1_kernel<<<SB, 1024, 0, stream>>>(deg, rp, bsum, N);
    scan_p2_kernel<<<1, 64, 0, stream>>>(bsum, SB);
    scan_p3_kernel<<<SB, 1024, 0, stream>>>(deg, rp, cursor, bsum, dinv, cinv, N);
    fill_csr_kernel<<<(E + 255) / 256, 256, 0, stream>>>(row, col, cursor, colS, E);

    // ---- prep ----
    f32_to_f16_kernel<<<(N * 32 + 255) / 256, 256, 0, stream>>>(x, Xb, N * 32);
    prep_w_kernel<<<(128 * 128 + 255) / 256, 256, 0, stream>>>(W0, 128, nullptr, 0, 128, 128, Wt0);
    prep_w_kernel<<<(256 * 256 + 255) / 256, 256, 0, stream>>>(W1, 128, R1, 128, 256, 256, Wt1);
    prep_w_kernel<<<(256 * 512 + 255) / 256, 256, 0, stream>>>(W2, 256, R2, 256, 256, 256, Wt2);
    prep_w_kernel<<<(256 * 256 + 255) / 256, 256, 0, stream>>>(W3, 256, nullptr, 0, 256, 256, Wt3);
    prep_w2_kernel<<<(256 * 256) / 256, 256, 0, stream>>>(W4, R4, Wt4p);
    prep_biasP_kernel<<<1, 256, 0, stream>>>(b4, biasP);

    dim3 aggGrid((N + 3) / 4);
    dim3 gM((N + 255) / 256, 1);

    // ---- L0 (GCN): Hb = f16( x + a0*(gcn_agg(x)@W0 + b0) ) ----
    agg_f16_kernel<128, true, 0><<<aggGrid, 256, 0, stream>>>(
        Xb, 128, rp, colS, dinv, dinv, Ab, 128, nullptr, 0, N);
    mfma_gemm_kernel<128, 2, false, false, true><<<gM, 512, 0, stream>>>(
        Ab, 128, 128, nullptr, 0, 0, Wt0, b0, x, 128, alpha, 0,
        nullptr, Hb, 128, N, 128);

    // ---- L1 (SAGE 128->256): Gb = relu([mean(Hb)|Hb]@[W1;R1]+b1) ----
    agg_f16_kernel<128, false, 0><<<aggGrid, 256, 0, stream>>>(
        Hb, 128, rp, colS, nullptr, cinv, Ab, 128, nullptr, 0, N);
    mfma_gemm_kernel<256, 1, false, false, true><<<gM, 1024, 0, stream>>>(
        Ab, 128, 128, Hb, 128, 128, Wt1, b1, nullptr, 0, nullptr, 0,
        nullptr, Gb, 256, N, 256);

    // ---- L2 (SAGE 256->256): Pb = relu([mean(Gb)|Gb]@[W2;R2]+b2) ----
    agg_f16_kernel<256, false, 0><<<aggGrid, 256, 0, stream>>>(
        Gb, 256, rp, colS, nullptr, cinv, Ab, 256, nullptr, 0, N);
    mfma_gemm_kernel<256, 1, false, false, true><<<gM, 1024, 0, stream>>>(
        Ab, 256, 256, Gb, 256, 256, Wt2, b2, nullptr, 0, nullptr, 0,
        nullptr, Pb, 256, N, 256);

    // ---- L3 (GCN): Gb = Pb + a3*(gcn_agg(Pb)@W3 + b3) ----
    agg_f16_kernel<256, true, 0><<<aggGrid, 256, 0, stream>>>(
        Pb, 256, rp, colS, dinv, dinv, Ab, 256, nullptr, 0, N);
    mfma_gemm_kernel<256, 2, true, false, true><<<gM, 1024, 0, stream>>>(
        Ab, 256, 256, nullptr, 0, 0, Wt3, b3, Pb, 256, alpha, 3,
        nullptr, Gb, 256, N, 256);

    // ---- L4 (SAGE 256->112), commuted: T = Gb@W4 (f16), U = Gb@R4+b4 ->
    //      d_out; then d_out += cinv * A * T ----
    mfma_gemm_kernel<256, 3, false, false, false><<<gM, 1024, 0, stream>>>(
        Gb, 256, 256, nullptr, 0, 0, Wt4p, biasP, nullptr, 112, nullptr, 0,
        (float*)d_out, Ab, 128, N, 224);
    agg_f16_kernel<128, false, 1><<<aggGrid, 256, 0, stream>>>(
        Ab, 128, rp, colS, nullptr, cinv, nullptr, 0, (float*)d_out, 112, N);
}

// Round 9
// 690.811 us; speedup vs baseline: 1.0083x; 1.0083x over previous
//
#include <hip/hip_runtime.h>

// ---------------------------------------------------------------------------
// SAGE_Re GNN forward, R13.
// - GEMM: BM=256 x BN=128, 512 threads (8 waves, 4M x 2N), per-wave 64x64.
//   Halves B-restage requests vs BM=128 while KEEPING 2 blocks/CU
//   (72KB LDS = As 48 + Bs 24; R12's 96KB/1-block mistake corrected).
//   3-stage dist-3 counted-vmcnt pipeline; corrected <=2-way swizzle
//   (seg ^= (row>>1)&3).
// - agg: R11 unconditional UNR=4 gathers (at ~10 B/cyc/CU load-path
//   ceiling; invariant to instruction count).
// - L4 commuted (R10); fp16 + swapped-operand C^T epilogue (R9).
// - CSR: 3-phase multi-block scan (R5).
// ---------------------------------------------------------------------------

typedef _Float16 __attribute__((ext_vector_type(8))) f16x8;
typedef _Float16 __attribute__((ext_vector_type(2))) f16x2;
typedef __attribute__((ext_vector_type(4))) float f32x4;

__device__ __forceinline__ unsigned short f2h(float f) {
    union { _Float16 h; unsigned short u; } v; v.h = (_Float16)f; return v.u;
}
__device__ __forceinline__ float h2f(unsigned short u) {
    union { unsigned short u; _Float16 h; } v; v.u = u; return (float)v.h;
}

// ---------------- CSR build ----------------

__global__ __launch_bounds__(256) void zero_int_kernel(int* __restrict__ p, int n)
{
    int i = blockIdx.x * 256 + threadIdx.x;
    if (i < n) p[i] = 0;
}

__global__ __launch_bounds__(256) void count_deg_kernel(
    const int* __restrict__ row, int* __restrict__ deg, int E)
{
    int e = blockIdx.x * 256 + threadIdx.x;
    if (e < E) atomicAdd(&deg[row[e]], 1);
}

__global__ __launch_bounds__(1024) void scan_p1_kernel(
    const int* __restrict__ deg, int* __restrict__ rp,
    int* __restrict__ bsum, int n)
{
    __shared__ int wsum[16];
    int t = threadIdx.x, lane = t & 63, w = t >> 6;
    int base = blockIdx.x * 2048;
    int carry = 0;
    #pragma unroll
    for (int half = 0; half < 2; ++half) {
        int i = base + half * 1024 + t;
        int xv = (i < n) ? deg[i] : 0;
        int s = xv;
        #pragma unroll
        for (int off = 1; off < 64; off <<= 1) {
            int v = __shfl_up(s, off, 64);
            if (lane >= off) s += v;
        }
        if (lane == 63) wsum[w] = s;
        __syncthreads();
        if (w == 0 && lane < 16) {
            int ws = wsum[lane];
            #pragma unroll
            for (int off = 1; off < 16; off <<= 1) {
                int v = __shfl_up(ws, off, 64);
                if (lane >= off) ws += v;
            }
            wsum[lane] = ws;
        }
        __syncthreads();
        int wo = (w == 0) ? 0 : wsum[w - 1];
        if (i < n) rp[i + 1] = carry + wo + s;
        carry += wsum[15];
        if (half == 0) __syncthreads();
    }
    if (t == 0) bsum[blockIdx.x] = carry;
}

__global__ __launch_bounds__(64) void scan_p2_kernel(int* __restrict__ bsum, int B)
{
    int lane = threadIdx.x;
    int v = (lane < B) ? bsum[lane] : 0;
    int s = v;
    #pragma unroll
    for (int off = 1; off < 64; off <<= 1) {
        int u = __shfl_up(s, off, 64);
        if (lane >= off) s += u;
    }
    if (lane < B) bsum[lane] = s - v;
}

__global__ __launch_bounds__(1024) void scan_p3_kernel(
    const int* __restrict__ deg, int* __restrict__ rp,
    int* __restrict__ cursor, const int* __restrict__ bsum,
    float* __restrict__ dinv, float* __restrict__ cinv, int n)
{
    int boff = bsum[blockIdx.x];
    int base = blockIdx.x * 2048;
    #pragma unroll
    for (int half = 0; half < 2; ++half) {
        int i = base + half * 1024 + threadIdx.x;
        if (i < n) {
            int d = deg[i];
            int incl = rp[i + 1] + boff;
            rp[i + 1] = incl;
            cursor[i] = incl - d;
            float df = (float)d;
            dinv[i] = (d > 0) ? rsqrtf(df) : 0.0f;
            cinv[i] = 1.0f / fmaxf(df, 1.0f);
        }
    }
    if (blockIdx.x == 0 && threadIdx.x == 0) rp[0] = 0;
}

__global__ __launch_bounds__(256) void fill_csr_kernel(
    const int* __restrict__ row, const int* __restrict__ col,
    int* __restrict__ cursor, int* __restrict__ colS, int E)
{
    int e = blockIdx.x * 256 + threadIdx.x;
    if (e < E) {
        int p = atomicAdd(&cursor[row[e]], 1);
        colS[p] = col[e];
    }
}

// ---------------- prep ----------------

__global__ __launch_bounds__(256) void f32_to_f16_kernel(
    const float* __restrict__ src, unsigned short* __restrict__ dst, int n4)
{
    int i = blockIdx.x * 256 + threadIdx.x;
    if (i >= n4) return;
    float4 v = ((const float4*)src)[i];
    ushort4 o;
    o.x = f2h(v.x); o.y = f2h(v.y); o.z = f2h(v.z); o.w = f2h(v.w);
    ((ushort4*)dst)[i] = o;
}

__global__ __launch_bounds__(256) void prep_w_kernel(
    const float* __restrict__ S1, int K1,
    const float* __restrict__ S2, int K2,
    int Nout, int Npad, unsigned short* __restrict__ dst)
{
    int Ktot = K1 + K2;
    int idx = blockIdx.x * 256 + threadIdx.x;
    if (idx >= Npad * Ktot) return;
    int n = idx / Ktot, k = idx - n * Ktot;
    float v = 0.0f;
    if (n < Nout)
        v = (k < K1) ? S1[(size_t)k * Nout + n] : S2[(size_t)(k - K1) * Nout + n];
    dst[idx] = f2h(v);
}

// L4 weight prep: dst is 256 rows (n) x 256 cols (k):
//   n<112 -> W4[:,n] ; 112<=n<224 -> R4[:,n-112] ; else 0.
__global__ __launch_bounds__(256) void prep_w2_kernel(
    const float* __restrict__ W4, const float* __restrict__ R4,
    unsigned short* __restrict__ dst)
{
    int idx = blockIdx.x * 256 + threadIdx.x;   // 256*256 total
    int nrow = idx >> 8, k = idx & 255;
    float v = 0.0f;
    if (nrow < 112)      v = W4[(size_t)k * 112 + nrow];
    else if (nrow < 224) v = R4[(size_t)k * 112 + (nrow - 112)];
    dst[idx] = f2h(v);
}

__global__ __launch_bounds__(256) void prep_biasP_kernel(
    const float* __restrict__ b4, float* __restrict__ biasP)
{
    int i = threadIdx.x;   // 256
    biasP[i] = (i >= 112 && i < 224) ? b4[i - 112] : 0.0f;
}

// ---------------- aggregation: wave per node, packed-f16 accumulation ------
// OUT_MODE 0: out f16 (acc * nscale).   OUT_MODE 1: fout (f32, width 112)
//   += nscale * acc   (RMW of the GEMM-produced U term).

template <int C, bool HAS_ES, int OUT_MODE>
__global__ __launch_bounds__(256) void agg_f16_kernel(
    const unsigned short* __restrict__ h, int ldh,
    const int* __restrict__ rp, const int* __restrict__ cols,
    const float* __restrict__ escale, const float* __restrict__ nscale,
    unsigned short* __restrict__ out, int ldo,
    float* __restrict__ fout, int ldof, int n)
{
    constexpr int LPE = (C == 256) ? 32 : 16;  // lanes per edge
    constexpr int EPG = 64 / LPE;              // edges per group (2 or 4)
    constexpr int UNR = 4;                     // gathers in flight per lane
    int node = blockIdx.x * 4 + (threadIdx.x >> 6);
    if (node >= n) return;
    int lane = threadIdx.x & 63;
    int grp = lane / LPE, sub = lane % LPE;
    const unsigned short* hc = h + sub * 8;

    int s = rp[node], e = rp[node + 1];
    const _Float16 hz = (_Float16)0.0f;
    f16x2 zz = { hz, hz };
    f16x2 acc2[4];
    #pragma unroll
    for (int k = 0; k < 4; ++k) acc2[k] = zz;

    for (int i = s; i < e; i += UNR * EPG) {
        int cc[UNR]; f16x2 ssv[UNR]; uint4 uu[UNR];
        #pragma unroll
        for (int u = 0; u < UNR; ++u) {
            int ii = i + u * EPG + grp;
            bool valid = ii < e;
            int c = valid ? cols[ii] : 0;
            cc[u] = c;
            float sc = valid ? (HAS_ES ? escale[c] : 1.0f) : 0.0f;
            _Float16 sh = (_Float16)sc;
            f16x2 sv = { sh, sh };
            ssv[u] = sv;
        }
        #pragma unroll
        for (int u = 0; u < UNR; ++u)
            uu[u] = *(const uint4*)(hc + (size_t)cc[u] * ldh);
        #pragma unroll
        for (int u = 0; u < UNR; ++u) {
            union { uint4 q; f16x2 hh[4]; } cv; cv.q = uu[u];
            #pragma unroll
            for (int p = 0; p < 4; ++p)
                acc2[p] += cv.hh[p] * ssv[u];       // v_pk_fma_f16
        }
    }

    #pragma unroll
    for (int k = 0; k < 4; ++k) {
        union { f16x2 h2; float f; } a, b;
        a.h2 = acc2[k];
        if (EPG == 4) { b.f = __shfl_xor(a.f, 16, 64); a.h2 = a.h2 + b.h2; }
        b.f = __shfl_xor(a.f, 32, 64); a.h2 = a.h2 + b.h2;
        acc2[k] = a.h2;
    }

    if (OUT_MODE == 0) {
        if (grp == 0) {
            _Float16 nh = (_Float16)nscale[node];
            f16x2 nn = { nh, nh };
            union { uint4 q; f16x2 hh[4]; } o;
            #pragma unroll
            for (int p = 0; p < 4; ++p) o.hh[p] = acc2[p] * nn;
            *(uint4*)(out + (size_t)node * ldo + sub * 8) = o.q;
        }
    } else {
        // fout[node][sub*8 .. +7] += nscale * acc  (cols >= 112 skipped)
        if (grp == 0 && sub < 14) {
            float cs = nscale[node];
            float* U = fout + (size_t)node * ldof + sub * 8;
            float4 u0 = *(float4*)U;
            float4 u1 = *(float4*)(U + 4);
            u0.x += cs * (float)acc2[0][0];
            u0.y += cs * (float)acc2[0][1];
            u0.z += cs * (float)acc2[1][0];
            u0.w += cs * (float)acc2[1][1];
            u1.x += cs * (float)acc2[2][0];
            u1.y += cs * (float)acc2[2][1];
            u1.z += cs * (float)acc2[3][0];
            u1.w += cs * (float)acc2[3][1];
            *(float4*)U = u0;
            *(float4*)(U + 4) = u1;
        }
    }
}

// ---------------- fp16 MFMA GEMM, 256x128 tile, 3-stage dist-3 pipeline ----
// 512 threads = 8 waves (4 M-waves x 2 N-waves), per-wave 64x64 output.
// LDS 72KB -> 2 blocks/CU (the R12 lesson: never drop below 2).
// MFMA operands SWAPPED: acc = mfma(B_frag, A_frag) = C^T fragment.
// Swizzle: LDS[row][sp] = global[row][sp ^ ((row>>1)&3)]; store side fetches
// src seg (t&3)^((t>>3)&3); read side sp = q ^ ((l16>>1)&3). <=2-way banks.
// EPI: 0 none, 1 relu, 2 residual (res + alpha*v), 3 dual-output L4
//   (n<112 -> f16 T at outb/ldo; n>=112 -> f32 U at outf/ldres).

__device__ __forceinline__ void g2l16(const unsigned short* g, unsigned short* l) {
    __builtin_amdgcn_global_load_lds(
        (const __attribute__((address_space(1))) unsigned int*)g,
        (__attribute__((address_space(3))) unsigned int*)l, 16, 0, 0);
}

template <int EPI, bool RES_F16, bool WF32, bool WB16>
__global__ __launch_bounds__(512) void mfma_gemm_kernel(
    const unsigned short* __restrict__ A1, int K1, int lda1,
    const unsigned short* __restrict__ A2, int K2, int lda2,
    const unsigned short* __restrict__ Bt,
    const float* __restrict__ bias,
    const void* __restrict__ res, int ldres,
    const float* __restrict__ alpha_ptr, int alpha_idx,
    float* __restrict__ outf, unsigned short* __restrict__ outb, int ldo,
    int M, int Nout)
{
    __shared__ unsigned short As[3][256 * 32];   // 48 KB
    __shared__ unsigned short Bs[3][128 * 32];   // 24 KB
    int t = threadIdx.x;
    int m0 = blockIdx.x * 256, n0 = blockIdx.y * 128;
    int Ktot = K1 + K2;
    int w = t >> 6, lane = t & 63;
    int wm = w & 3, wn = w >> 2;         // 4 M-waves, 2 N-waves
    int q = lane >> 4, l16 = lane & 15;

    // store-side swizzle: thread t stages row (t>>2), fetching source 16B-seg
    // (t&3)^((t>>3)&3) -> LDS[row][sp] = global[row][sp ^ ((row>>1)&3)].
    int koff = (((t & 3) ^ ((t >> 3) & 3)) * 8);
    int rsub = t >> 2;                   // staged row within pass: 0..127

    f32x4 acc[4][4];
    #pragma unroll
    for (int i = 0; i < 4; ++i)
        #pragma unroll
        for (int j = 0; j < 4; ++j)
            #pragma unroll
            for (int r = 0; r < 4; ++r) acc[i][j][r] = 0.0f;

    const int KC = Ktot >> 5;

    auto issue = [&](int kc, int p) {
        int k0 = kc * 32;
        const unsigned short* Ap; int lda, kk;
        if (k0 < K1) { Ap = A1; lda = lda1; kk = k0; }
        else         { Ap = A2; lda = lda2; kk = k0 - K1; }
        #pragma unroll
        for (int a = 0; a < 2; ++a) {    // 2 passes x 128 rows = 256 A rows
            int gm = m0 + a * 128 + rsub; if (gm >= M) gm = M - 1;
            g2l16(Ap + (size_t)gm * lda + kk + koff,
                  &As[p][a * (128 * 32) + w * 512]);
        }
        {
            int gn = n0 + rsub;          // < Npad by construction
            g2l16(Bt + (size_t)gn * Ktot + k0 + koff, &Bs[p][w * 512]);
        }
    };

    // read-side swizzle: sp = q ^ ((l16>>1)&3); (row>>1)&3 == (l16>>1)&3
    const int cq = (q ^ ((l16 >> 1) & 3)) * 8;
    const int rbA = (wm * 64 + l16) * 32 + cq;
    const int rbB = (wn * 64 + l16) * 32 + cq;

    issue(0, 0);
    if (KC > 1) issue(1, 1);
    if (KC > 2) issue(2, 2);

    int p = 0;
    for (int kc = 0; kc < KC; ++kc) {
        int rem = KC - 1 - kc;   // chunks issued after kc (capped at 2)
        // 3 loads/thread/chunk: steady vmcnt(6), tail 3, last 0.
        if (rem >= 2)      asm volatile("s_waitcnt vmcnt(6)" ::: "memory");
        else if (rem == 1) asm volatile("s_waitcnt vmcnt(3)" ::: "memory");
        else               asm volatile("s_waitcnt vmcnt(0)" ::: "memory");
        __builtin_amdgcn_s_barrier();      // B1: chunk-kc data visible everywhere
        asm volatile("" ::: "memory");

        f16x8 af[4], bfr[4];
        #pragma unroll
        for (int i = 0; i < 4; ++i)
            af[i] = *(const f16x8*)&As[p][rbA + i * 512];
        #pragma unroll
        for (int j = 0; j < 4; ++j)
            bfr[j] = *(const f16x8*)&Bs[p][rbB + j * 512];

        asm volatile("s_waitcnt lgkmcnt(0)" ::: "memory");
        __builtin_amdgcn_s_barrier();      // B2: all waves done reading buf p
        asm volatile("" ::: "memory");
        if (kc + 3 < KC) issue(kc + 3, p); // distance-3 prefetch into freed buf

        __builtin_amdgcn_s_setprio(1);
        #pragma unroll
        for (int i = 0; i < 4; ++i)
            #pragma unroll
            for (int j = 0; j < 4; ++j)
                acc[i][j] = __builtin_amdgcn_mfma_f32_16x16x32_f16(
                    bfr[j], af[i], acc[i][j], 0, 0, 0);   // SWAPPED -> C^T frag
        __builtin_amdgcn_s_setprio(0);

        p = (p == 2) ? 0 : p + 1;
    }

    // Epilogue (swapped layout): lane (q,l16) holds, for tile (i,j),
    // m = m0 + wm*64 + i*16 + l16 (fixed), n = n0 + wn*64 + j*16 + q*4 + r.
    float alpha = 0.0f;
    if (EPI == 2) alpha = alpha_ptr[alpha_idx];
    #pragma unroll
    for (int i = 0; i < 4; ++i) {
        int m = m0 + wm * 64 + i * 16 + l16;
        if (m >= M) continue;
        #pragma unroll
        for (int j = 0; j < 4; ++j) {
            int nb = n0 + wn * 64 + j * 16 + q * 4;
            if (nb >= Nout) continue;      // Nout in {128,256,224}: mult of 16
            float4 bv = *(const float4*)&bias[nb];
            float v0 = acc[i][j][0] + bv.x;
            float v1 = acc[i][j][1] + bv.y;
            float v2 = acc[i][j][2] + bv.z;
            float v3 = acc[i][j][3] + bv.w;
            if (EPI == 3) {
                if (nb < 112) {
                    *(ushort4*)&outb[(size_t)m * ldo + nb] =
                        make_ushort4(f2h(v0), f2h(v1), f2h(v2), f2h(v3));
                } else {
                    *(float4*)&outf[(size_t)m * ldres + (nb - 112)] =
                        make_float4(v0, v1, v2, v3);
                }
                continue;
            }
            if (EPI == 1) {
                v0 = fmaxf(v0, 0.0f); v1 = fmaxf(v1, 0.0f);
                v2 = fmaxf(v2, 0.0f); v3 = fmaxf(v3, 0.0f);
            }
            if (EPI == 2) {
                if (RES_F16) {
                    ushort4 rr = *(const ushort4*)
                        ((const unsigned short*)res + (size_t)m * ldres + nb);
                    v0 = h2f(rr.x) + alpha * v0;
                    v1 = h2f(rr.y) + alpha * v1;
                    v2 = h2f(rr.z) + alpha * v2;
                    v3 = h2f(rr.w) + alpha * v3;
                } else {
                    float4 rr = *(const float4*)
                        ((const float*)res + (size_t)m * ldres + nb);
                    v0 = rr.x + alpha * v0;
                    v1 = rr.y + alpha * v1;
                    v2 = rr.z + alpha * v2;
                    v3 = rr.w + alpha * v3;
                }
            }
            if (WF32) {
                *(float4*)&outf[(size_t)m * ldo + nb] = make_float4(v0, v1, v2, v3);
            }
            if (WB16) {
                *(ushort4*)&outb[(size_t)m * ldo + nb] =
                    make_ushort4(f2h(v0), f2h(v1), f2h(v2), f2h(v3));
            }
        }
    }
}

// ---------------------------------------------------------------------------

extern "C" void kernel_launch(void* const* d_in, const int* in_sizes, int n_in,
                              void* d_out, int out_size, void* d_ws, size_t ws_size,
                              hipStream_t stream)
{
    const float* x      = (const float*)d_in[0];
    const int*   ei     = (const int*)d_in[1];
    const float* alpha  = (const float*)d_in[2];
    const float* W0     = (const float*)d_in[3];
    const float* b0     = (const float*)d_in[4];
    const float* W1     = (const float*)d_in[5];
    const float* R1     = (const float*)d_in[6];
    const float* b1     = (const float*)d_in[7];
    const float* W2     = (const float*)d_in[8];
    const float* R2     = (const float*)d_in[9];
    const float* b2     = (const float*)d_in[10];
    const float* W3     = (const float*)d_in[11];
    const float* b3     = (const float*)d_in[12];
    const float* W4     = (const float*)d_in[13];
    const float* R4     = (const float*)d_in[14];
    const float* b4     = (const float*)d_in[15];

    const int N = in_sizes[0] / 128;
    const int E = in_sizes[1] / 2;
    const int* row = ei;
    const int* col = ei + E;

    size_t off = 0;
    auto alloc = [&](size_t bytes) -> void* {
        void* p = (char*)d_ws + off;
        off += (bytes + 255) & ~(size_t)255;
        return p;
    };
    int*   deg    = (int*)alloc((size_t)N * 4);
    int*   rp     = (int*)alloc((size_t)(N + 1) * 4);
    int*   cursor = (int*)alloc((size_t)N * 4);
    int*   colS   = (int*)alloc((size_t)E * 4);
    int*   bsum   = (int*)alloc((size_t)64 * 4);
    float* dinv   = (float*)alloc((size_t)N * 4);
    float* cinv   = (float*)alloc((size_t)N * 4);
    unsigned short* Wt0 = (unsigned short*)alloc((size_t)128 * 128 * 2);
    unsigned short* Wt1 = (unsigned short*)alloc((size_t)256 * 256 * 2);
    unsigned short* Wt2 = (unsigned short*)alloc((size_t)256 * 512 * 2);
    unsigned short* Wt3 = (unsigned short*)alloc((size_t)256 * 256 * 2);
    unsigned short* Wt4p= (unsigned short*)alloc((size_t)256 * 256 * 2);
    float* biasP  = (float*)alloc((size_t)256 * 4);
    unsigned short* Xb  = (unsigned short*)alloc((size_t)N * 128 * 2);
    unsigned short* Gb  = (unsigned short*)alloc((size_t)N * 256 * 2);
    unsigned short* Pb  = (unsigned short*)alloc((size_t)N * 256 * 2);
    unsigned short* Ab  = (unsigned short*)alloc((size_t)N * 256 * 2);
    unsigned short* Hb  = Xb;  // alias: Xb only read by L0 agg before Hb written
    (void)ws_size;

    // ---- CSR build ----
    const int SB = (N + 2047) / 2048;
    zero_int_kernel<<<(N + 255) / 256, 256, 0, stream>>>(deg, N);
    count_deg_kernel<<<(E + 255) / 256, 256, 0, stream>>>(row, deg, E);
    scan_p1_kernel<<<SB, 1024, 0, stream>>>(deg, rp, bsum, N);
    scan_p2_kernel<<<1, 64, 0, stream>>>(bsum, SB);
    scan_p3_kernel<<<SB, 1024, 0, stream>>>(deg, rp, cursor, bsum, dinv, cinv, N);
    fill_csr_kernel<<<(E + 255) / 256, 256, 0, stream>>>(row, col, cursor, colS, E);

    // ---- prep ----
    f32_to_f16_kernel<<<(N * 32 + 255) / 256, 256, 0, stream>>>(x, Xb, N * 32);
    prep_w_kernel<<<(128 * 128 + 255) / 256, 256, 0, stream>>>(W0, 128, nullptr, 0, 128, 128, Wt0);
    prep_w_kernel<<<(256 * 256 + 255) / 256, 256, 0, stream>>>(W1, 128, R1, 128, 256, 256, Wt1);
    prep_w_kernel<<<(256 * 512 + 255) / 256, 256, 0, stream>>>(W2, 256, R2, 256, 256, 256, Wt2);
    prep_w_kernel<<<(256 * 256 + 255) / 256, 256, 0, stream>>>(W3, 256, nullptr, 0, 256, 256, Wt3);
    prep_w2_kernel<<<(256 * 256) / 256, 256, 0, stream>>>(W4, R4, Wt4p);
    prep_biasP_kernel<<<1, 256, 0, stream>>>(b4, biasP);

    dim3 aggGrid((N + 3) / 4);
    dim3 g1((N + 255) / 256, 1), g2((N + 255) / 256, 2);

    // ---- L0 (GCN): Hb = f16( x + a0*(gcn_agg(x)@W0 + b0) ) ----
    agg_f16_kernel<128, true, 0><<<aggGrid, 256, 0, stream>>>(
        Xb, 128, rp, colS, dinv, dinv, Ab, 128, nullptr, 0, N);
    mfma_gemm_kernel<2, false, false, true><<<g1, 512, 0, stream>>>(
        Ab, 128, 128, nullptr, 0, 0, Wt0, b0, x, 128, alpha, 0,
        nullptr, Hb, 128, N, 128);

    // ---- L1 (SAGE 128->256): Gb = relu([mean(Hb)|Hb]@[W1;R1]+b1) ----
    agg_f16_kernel<128, false, 0><<<aggGrid, 256, 0, stream>>>(
        Hb, 128, rp, colS, nullptr, cinv, Ab, 128, nullptr, 0, N);
    mfma_gemm_kernel<1, false, false, true><<<g2, 512, 0, stream>>>(
        Ab, 128, 128, Hb, 128, 128, Wt1, b1, nullptr, 0, nullptr, 0,
        nullptr, Gb, 256, N, 256);

    // ---- L2 (SAGE 256->256): Pb = relu([mean(Gb)|Gb]@[W2;R2]+b2) ----
    agg_f16_kernel<256, false, 0><<<aggGrid, 256, 0, stream>>>(
        Gb, 256, rp, colS, nullptr, cinv, Ab, 256, nullptr, 0, N);
    mfma_gemm_kernel<1, false, false, true><<<g2, 512, 0, stream>>>(
        Ab, 256, 256, Gb, 256, 256, Wt2, b2, nullptr, 0, nullptr, 0,
        nullptr, Pb, 256, N, 256);

    // ---- L3 (GCN): Gb = Pb + a3*(gcn_agg(Pb)@W3 + b3) ----
    agg_f16_kernel<256, true, 0><<<aggGrid, 256, 0, stream>>>(
        Pb, 256, rp, colS, dinv, dinv, Ab, 256, nullptr, 0, N);
    mfma_gemm_kernel<2, true, false, true><<<g2, 512, 0, stream>>>(
        Ab, 256, 256, nullptr, 0, 0, Wt3, b3, Pb, 256, alpha, 3,
        nullptr, Gb, 256, N, 256);

    // ---- L4 (SAGE 256->112), commuted: T = Gb@W4 (f16), U = Gb@R4+b4 ->
    //      d_out; then d_out += cinv * A * T ----
    mfma_gemm_kernel<3, false, false, false><<<g2, 512, 0, stream>>>(
        Gb, 256, 256, nullptr, 0, 0, Wt4p, biasP, nullptr, 112, nullptr, 0,
        (float*)d_out, Ab, 128, N, 224);
    agg_f16_kernel<128, false, 1><<<aggGrid, 256, 0, stream>>>(
        Ab, 128, rp, colS, nullptr, cinv, nullptr, 0, (float*)d_out, 112, N);
}

// Round 10
// 678.406 us; speedup vs baseline: 1.0268x; 1.0183x over previous
//
#include <hip/hip_runtime.h>

// ---------------------------------------------------------------------------
// SAGE_Re GNN forward, R14 = R11 (best measured, 675us) + corrected LDS
// swizzle ONLY.
// - GEMM: 128 x BN tile (BN=128/256), 2*BN threads, 3-stage dist-3
//   counted-vmcnt pipeline. Swizzle fixed: seg ^= (row>>1)&3 (R11's row&3
//   left lanes {0,4,8,12} colliding -> the invariant 3.2M bank conflicts).
// - agg: unconditional UNR=4 gathers (at ~10 B/cyc/CU load-path ceiling;
//   proven invariant to instruction count).
// - L4 commuted (R10); fp16 + swapped-operand C^T epilogue (R9).
// - CSR: 3-phase multi-block scan (R5).
// ---------------------------------------------------------------------------

typedef _Float16 __attribute__((ext_vector_type(8))) f16x8;
typedef _Float16 __attribute__((ext_vector_type(2))) f16x2;
typedef __attribute__((ext_vector_type(4))) float f32x4;

__device__ __forceinline__ unsigned short f2h(float f) {
    union { _Float16 h; unsigned short u; } v; v.h = (_Float16)f; return v.u;
}
__device__ __forceinline__ float h2f(unsigned short u) {
    union { unsigned short u; _Float16 h; } v; v.u = u; return (float)v.h;
}

// ---------------- CSR build ----------------

__global__ __launch_bounds__(256) void zero_int_kernel(int* __restrict__ p, int n)
{
    int i = blockIdx.x * 256 + threadIdx.x;
    if (i < n) p[i] = 0;
}

__global__ __launch_bounds__(256) void count_deg_kernel(
    const int* __restrict__ row, int* __restrict__ deg, int E)
{
    int e = blockIdx.x * 256 + threadIdx.x;
    if (e < E) atomicAdd(&deg[row[e]], 1);
}

__global__ __launch_bounds__(1024) void scan_p1_kernel(
    const int* __restrict__ deg, int* __restrict__ rp,
    int* __restrict__ bsum, int n)
{
    __shared__ int wsum[16];
    int t = threadIdx.x, lane = t & 63, w = t >> 6;
    int base = blockIdx.x * 2048;
    int carry = 0;
    #pragma unroll
    for (int half = 0; half < 2; ++half) {
        int i = base + half * 1024 + t;
        int xv = (i < n) ? deg[i] : 0;
        int s = xv;
        #pragma unroll
        for (int off = 1; off < 64; off <<= 1) {
            int v = __shfl_up(s, off, 64);
            if (lane >= off) s += v;
        }
        if (lane == 63) wsum[w] = s;
        __syncthreads();
        if (w == 0 && lane < 16) {
            int ws = wsum[lane];
            #pragma unroll
            for (int off = 1; off < 16; off <<= 1) {
                int v = __shfl_up(ws, off, 64);
                if (lane >= off) ws += v;
            }
            wsum[lane] = ws;
        }
        __syncthreads();
        int wo = (w == 0) ? 0 : wsum[w - 1];
        if (i < n) rp[i + 1] = carry + wo + s;
        carry += wsum[15];
        if (half == 0) __syncthreads();
    }
    if (t == 0) bsum[blockIdx.x] = carry;
}

__global__ __launch_bounds__(64) void scan_p2_kernel(int* __restrict__ bsum, int B)
{
    int lane = threadIdx.x;
    int v = (lane < B) ? bsum[lane] : 0;
    int s = v;
    #pragma unroll
    for (int off = 1; off < 64; off <<= 1) {
        int u = __shfl_up(s, off, 64);
        if (lane >= off) s += u;
    }
    if (lane < B) bsum[lane] = s - v;
}

__global__ __launch_bounds__(1024) void scan_p3_kernel(
    const int* __restrict__ deg, int* __restrict__ rp,
    int* __restrict__ cursor, const int* __restrict__ bsum,
    float* __restrict__ dinv, float* __restrict__ cinv, int n)
{
    int boff = bsum[blockIdx.x];
    int base = blockIdx.x * 2048;
    #pragma unroll
    for (int half = 0; half < 2; ++half) {
        int i = base + half * 1024 + threadIdx.x;
        if (i < n) {
            int d = deg[i];
            int incl = rp[i + 1] + boff;
            rp[i + 1] = incl;
            cursor[i] = incl - d;
            float df = (float)d;
            dinv[i] = (d > 0) ? rsqrtf(df) : 0.0f;
            cinv[i] = 1.0f / fmaxf(df, 1.0f);
        }
    }
    if (blockIdx.x == 0 && threadIdx.x == 0) rp[0] = 0;
}

__global__ __launch_bounds__(256) void fill_csr_kernel(
    const int* __restrict__ row, const int* __restrict__ col,
    int* __restrict__ cursor, int* __restrict__ colS, int E)
{
    int e = blockIdx.x * 256 + threadIdx.x;
    if (e < E) {
        int p = atomicAdd(&cursor[row[e]], 1);
        colS[p] = col[e];
    }
}

// ---------------- prep ----------------

__global__ __launch_bounds__(256) void f32_to_f16_kernel(
    const float* __restrict__ src, unsigned short* __restrict__ dst, int n4)
{
    int i = blockIdx.x * 256 + threadIdx.x;
    if (i >= n4) return;
    float4 v = ((const float4*)src)[i];
    ushort4 o;
    o.x = f2h(v.x); o.y = f2h(v.y); o.z = f2h(v.z); o.w = f2h(v.w);
    ((ushort4*)dst)[i] = o;
}

__global__ __launch_bounds__(256) void prep_w_kernel(
    const float* __restrict__ S1, int K1,
    const float* __restrict__ S2, int K2,
    int Nout, int Npad, unsigned short* __restrict__ dst)
{
    int Ktot = K1 + K2;
    int idx = blockIdx.x * 256 + threadIdx.x;
    if (idx >= Npad * Ktot) return;
    int n = idx / Ktot, k = idx - n * Ktot;
    float v = 0.0f;
    if (n < Nout)
        v = (k < K1) ? S1[(size_t)k * Nout + n] : S2[(size_t)(k - K1) * Nout + n];
    dst[idx] = f2h(v);
}

// L4 weight prep: dst is 256 rows (n) x 256 cols (k):
//   n<112 -> W4[:,n] ; 112<=n<224 -> R4[:,n-112] ; else 0.
__global__ __launch_bounds__(256) void prep_w2_kernel(
    const float* __restrict__ W4, const float* __restrict__ R4,
    unsigned short* __restrict__ dst)
{
    int idx = blockIdx.x * 256 + threadIdx.x;   // 256*256 total
    int nrow = idx >> 8, k = idx & 255;
    float v = 0.0f;
    if (nrow < 112)      v = W4[(size_t)k * 112 + nrow];
    else if (nrow < 224) v = R4[(size_t)k * 112 + (nrow - 112)];
    dst[idx] = f2h(v);
}

__global__ __launch_bounds__(256) void prep_biasP_kernel(
    const float* __restrict__ b4, float* __restrict__ biasP)
{
    int i = threadIdx.x;   // 256
    biasP[i] = (i >= 112 && i < 224) ? b4[i - 112] : 0.0f;
}

// ---------------- aggregation: wave per node, packed-f16 accumulation ------
// OUT_MODE 0: out f16 (acc * nscale).   OUT_MODE 1: fout (f32, width 112)
//   += nscale * acc   (RMW of the GEMM-produced U term).

template <int C, bool HAS_ES, int OUT_MODE>
__global__ __launch_bounds__(256) void agg_f16_kernel(
    const unsigned short* __restrict__ h, int ldh,
    const int* __restrict__ rp, const int* __restrict__ cols,
    const float* __restrict__ escale, const float* __restrict__ nscale,
    unsigned short* __restrict__ out, int ldo,
    float* __restrict__ fout, int ldof, int n)
{
    constexpr int LPE = (C == 256) ? 32 : 16;  // lanes per edge
    constexpr int EPG = 64 / LPE;              // edges per group (2 or 4)
    constexpr int UNR = 4;                     // gathers in flight per lane
    int node = blockIdx.x * 4 + (threadIdx.x >> 6);
    if (node >= n) return;
    int lane = threadIdx.x & 63;
    int grp = lane / LPE, sub = lane % LPE;
    const unsigned short* hc = h + sub * 8;

    int s = rp[node], e = rp[node + 1];
    const _Float16 hz = (_Float16)0.0f;
    f16x2 zz = { hz, hz };
    f16x2 acc2[4];
    #pragma unroll
    for (int k = 0; k < 4; ++k) acc2[k] = zz;

    for (int i = s; i < e; i += UNR * EPG) {
        int cc[UNR]; f16x2 ssv[UNR]; uint4 uu[UNR];
        #pragma unroll
        for (int u = 0; u < UNR; ++u) {
            int ii = i + u * EPG + grp;
            bool valid = ii < e;
            int c = valid ? cols[ii] : 0;
            cc[u] = c;
            float sc = valid ? (HAS_ES ? escale[c] : 1.0f) : 0.0f;
            _Float16 sh = (_Float16)sc;
            f16x2 sv = { sh, sh };
            ssv[u] = sv;
        }
        #pragma unroll
        for (int u = 0; u < UNR; ++u)
            uu[u] = *(const uint4*)(hc + (size_t)cc[u] * ldh);
        #pragma unroll
        for (int u = 0; u < UNR; ++u) {
            union { uint4 q; f16x2 hh[4]; } cv; cv.q = uu[u];
            #pragma unroll
            for (int p = 0; p < 4; ++p)
                acc2[p] += cv.hh[p] * ssv[u];       // v_pk_fma_f16
        }
    }

    #pragma unroll
    for (int k = 0; k < 4; ++k) {
        union { f16x2 h2; float f; } a, b;
        a.h2 = acc2[k];
        if (EPG == 4) { b.f = __shfl_xor(a.f, 16, 64); a.h2 = a.h2 + b.h2; }
        b.f = __shfl_xor(a.f, 32, 64); a.h2 = a.h2 + b.h2;
        acc2[k] = a.h2;
    }

    if (OUT_MODE == 0) {
        if (grp == 0) {
            _Float16 nh = (_Float16)nscale[node];
            f16x2 nn = { nh, nh };
            union { uint4 q; f16x2 hh[4]; } o;
            #pragma unroll
            for (int p = 0; p < 4; ++p) o.hh[p] = acc2[p] * nn;
            *(uint4*)(out + (size_t)node * ldo + sub * 8) = o.q;
        }
    } else {
        // fout[node][sub*8 .. +7] += nscale * acc  (cols >= 112 skipped)
        if (grp == 0 && sub < 14) {
            float cs = nscale[node];
            float* U = fout + (size_t)node * ldof + sub * 8;
            float4 u0 = *(float4*)U;
            float4 u1 = *(float4*)(U + 4);
            u0.x += cs * (float)acc2[0][0];
            u0.y += cs * (float)acc2[0][1];
            u0.z += cs * (float)acc2[1][0];
            u0.w += cs * (float)acc2[1][1];
            u1.x += cs * (float)acc2[2][0];
            u1.y += cs * (float)acc2[2][1];
            u1.z += cs * (float)acc2[3][0];
            u1.w += cs * (float)acc2[3][1];
            *(float4*)U = u0;
            *(float4*)(U + 4) = u1;
        }
    }
}

// ---------------- fp16 MFMA GEMM, 128 x BN tile, 3-stage dist-3 pipeline ----
// MFMA operands SWAPPED: acc = mfma(B_frag, A_frag) computes the C^T
// fragment, so each lane holds 4 consecutive n at fixed m -> wide stores.
// Swizzle: LDS[row][sp] = global[row][sp ^ ((row>>1)&3)]; store side fetches
// src seg (lane&3)^((lane>>3)&3) (staged row = lane>>2); read side
// sp = q ^ ((l16>>1)&3). <=2-way bank aliasing (free per m136).
// EPI: 0 none, 1 relu, 2 residual (res + alpha*v), 3 dual-output L4
//   (n<112 -> f16 T at outb/ldo; n>=112 -> f32 U at outf/ldres).

__device__ __forceinline__ void g2l16(const unsigned short* g, unsigned short* l) {
    __builtin_amdgcn_global_load_lds(
        (const __attribute__((address_space(1))) unsigned int*)g,
        (__attribute__((address_space(3))) unsigned int*)l, 16, 0, 0);
}

template <int BN, int EPI, bool RES_F16, bool WF32, bool WB16>
__global__ __launch_bounds__(2 * BN) void mfma_gemm_kernel(
    const unsigned short* __restrict__ A1, int K1, int lda1,
    const unsigned short* __restrict__ A2, int K2, int lda2,
    const unsigned short* __restrict__ Bt,
    const float* __restrict__ bias,
    const void* __restrict__ res, int ldres,
    const float* __restrict__ alpha_ptr, int alpha_idx,
    float* __restrict__ outf, unsigned short* __restrict__ outb, int ldo,
    int M, int Nout)
{
    constexpr int WAVES = BN / 32;       // 4 (BN=128) or 8 (BN=256)
    constexpr int AI = 256 / BN;         // A-stage instrs per wave: 2 or 1
    constexpr int L  = AI + 2;           // loads per chunk per wave: 4 or 3
    __shared__ unsigned short As[3][128 * 32];
    __shared__ unsigned short Bs[3][BN * 32];
    int t = threadIdx.x;
    int m0 = blockIdx.x * 128, n0 = blockIdx.y * BN;
    int Ktot = K1 + K2;
    int w = t >> 6, lane = t & 63;
    int wm = w & 1, wn = w >> 1;         // wn in 0..WAVES/2-1
    int q = lane >> 4, l16 = lane & 15;

    // store-side swizzle (corrected): lane stages row (lane>>2), fetching
    // source 16B-seg (lane&3)^((lane>>3)&3) -> LDS[row][sp] =
    // global[row][sp ^ ((row>>1)&3)].
    int koff = (((lane & 3) ^ ((lane >> 3) & 3)) * 8);
    int rsub = lane >> 2;                // row within 16-row stripe: 0..15

    f32x4 acc[4][4];
    #pragma unroll
    for (int i = 0; i < 4; ++i)
        #pragma unroll
        for (int j = 0; j < 4; ++j)
            #pragma unroll
            for (int r = 0; r < 4; ++r) acc[i][j][r] = 0.0f;

    const int KC = Ktot >> 5;

    auto issue = [&](int kc, int p) {
        int k0 = kc * 32;
        const unsigned short* Ap; int lda, kk;
        if (k0 < K1) { Ap = A1; lda = lda1; kk = k0; }
        else         { Ap = A2; lda = lda2; kk = k0 - K1; }
        #pragma unroll
        for (int a = 0; a < AI; ++a) {
            int rb = a * 16 * WAVES + w * 16;         // LDS row base (uniform/wave)
            int gm = m0 + rb + rsub; if (gm >= M) gm = M - 1;
            g2l16(Ap + (size_t)gm * lda + kk + koff, &As[p][rb * 32]);
        }
        #pragma unroll
        for (int b = 0; b < 2; ++b) {
            int rb = b * 16 * WAVES + w * 16;
            int gn = n0 + rb + rsub;                   // < Npad by construction
            g2l16(Bt + (size_t)gn * Ktot + k0 + koff, &Bs[p][rb * 32]);
        }
    };

    // read-side swizzle (corrected): sp = q ^ ((l16>>1)&3); row mod 16 == l16
    const int cq = (q ^ ((l16 >> 1) & 3)) * 8;
    const int rbA = (wm * 64 + l16) * 32 + cq;
    const int rbB = (wn * 64 + l16) * 32 + cq;

    issue(0, 0);
    if (KC > 1) issue(1, 1);
    if (KC > 2) issue(2, 2);

    int p = 0;
    for (int kc = 0; kc < KC; ++kc) {
        int rem = KC - 1 - kc;   // chunks issued after kc (capped at 2)
        // steady state: chunks kc, kc+1, kc+2 outstanding -> drain kc only.
        if (rem >= 2) {
            if constexpr (L == 4) asm volatile("s_waitcnt vmcnt(8)" ::: "memory");
            else                  asm volatile("s_waitcnt vmcnt(6)" ::: "memory");
        } else if (rem == 1) {
            if constexpr (L == 4) asm volatile("s_waitcnt vmcnt(4)" ::: "memory");
            else                  asm volatile("s_waitcnt vmcnt(3)" ::: "memory");
        } else {
            asm volatile("s_waitcnt vmcnt(0)" ::: "memory");
        }
        __builtin_amdgcn_s_barrier();      // B1: chunk-kc data visible everywhere
        asm volatile("" ::: "memory");

        f16x8 af[4], bfr[4];
        #pragma unroll
        for (int i = 0; i < 4; ++i)
            af[i] = *(const f16x8*)&As[p][rbA + i * 16 * 32];
        #pragma unroll
        for (int j = 0; j < 4; ++j)
            bfr[j] = *(const f16x8*)&Bs[p][rbB + j * 16 * 32];

        asm volatile("s_waitcnt lgkmcnt(0)" ::: "memory");
        __builtin_amdgcn_s_barrier();      // B2: all waves done reading buf p
        asm volatile("" ::: "memory");
        if (kc + 3 < KC) issue(kc + 3, p); // distance-3 prefetch into freed buf

        __builtin_amdgcn_s_setprio(1);
        #pragma unroll
        for (int i = 0; i < 4; ++i)
            #pragma unroll
            for (int j = 0; j < 4; ++j)
                acc[i][j] = __builtin_amdgcn_mfma_f32_16x16x32_f16(
                    bfr[j], af[i], acc[i][j], 0, 0, 0);   // SWAPPED -> C^T frag
        __builtin_amdgcn_s_setprio(0);

        p = (p == 2) ? 0 : p + 1;
    }

    // Epilogue (swapped layout): lane (q,l16) holds, for tile (i,j),
    // m = m0 + wm*64 + i*16 + l16 (fixed), n = n0 + wn*64 + j*16 + q*4 + r.
    float alpha = 0.0f;
    if (EPI == 2) alpha = alpha_ptr[alpha_idx];
    #pragma unroll
    for (int i = 0; i < 4; ++i) {
        int m = m0 + wm * 64 + i * 16 + l16;
        if (m >= M) continue;
        #pragma unroll
        for (int j = 0; j < 4; ++j) {
            int nb = n0 + wn * 64 + j * 16 + q * 4;
            if (nb >= Nout) continue;      // Nout in {128,256,224}: mult of 16
            float4 bv = *(const float4*)&bias[nb];
            float v0 = acc[i][j][0] + bv.x;
            float v1 = acc[i][j][1] + bv.y;
            float v2 = acc[i][j][2] + bv.z;
            float v3 = acc[i][j][3] + bv.w;
            if (EPI == 3) {
                if (nb < 112) {
                    *(ushort4*)&outb[(size_t)m * ldo + nb] =
                        make_ushort4(f2h(v0), f2h(v1), f2h(v2), f2h(v3));
                } else {
                    *(float4*)&outf[(size_t)m * ldres + (nb - 112)] =
                        make_float4(v0, v1, v2, v3);
                }
                continue;
            }
            if (EPI == 1) {
                v0 = fmaxf(v0, 0.0f); v1 = fmaxf(v1, 0.0f);
                v2 = fmaxf(v2, 0.0f); v3 = fmaxf(v3, 0.0f);
            }
            if (EPI == 2) {
                if (RES_F16) {
                    ushort4 rr = *(const ushort4*)
                        ((const unsigned short*)res + (size_t)m * ldres + nb);
                    v0 = h2f(rr.x) + alpha * v0;
                    v1 = h2f(rr.y) + alpha * v1;
                    v2 = h2f(rr.z) + alpha * v2;
                    v3 = h2f(rr.w) + alpha * v3;
                } else {
                    float4 rr = *(const float4*)
                        ((const float*)res + (size_t)m * ldres + nb);
                    v0 = rr.x + alpha * v0;
                    v1 = rr.y + alpha * v1;
                    v2 = rr.z + alpha * v2;
                    v3 = rr.w + alpha * v3;
                }
            }
            if (WF32) {
                *(float4*)&outf[(size_t)m * ldo + nb] = make_float4(v0, v1, v2, v3);
            }
            if (WB16) {
                *(ushort4*)&outb[(size_t)m * ldo + nb] =
                    make_ushort4(f2h(v0), f2h(v1), f2h(v2), f2h(v3));
            }
        }
    }
}

// ---------------------------------------------------------------------------

extern "C" void kernel_launch(void* const* d_in, const int* in_sizes, int n_in,
                              void* d_out, int out_size, void* d_ws, size_t ws_size,
                              hipStream_t stream)
{
    const float* x      = (const float*)d_in[0];
    const int*   ei     = (const int*)d_in[1];
    const float* alpha  = (const float*)d_in[2];
    const float* W0     = (const float*)d_in[3];
    const float* b0     = (const float*)d_in[4];
    const float* W1     = (const float*)d_in[5];
    const float* R1     = (const float*)d_in[6];
    const float* b1     = (const float*)d_in[7];
    const float* W2     = (const float*)d_in[8];
    const float* R2     = (const float*)d_in[9];
    const float* b2     = (const float*)d_in[10];
    const float* W3     = (const float*)d_in[11];
    const float* b3     = (const float*)d_in[12];
    const float* W4     = (const float*)d_in[13];
    const float* R4     = (const float*)d_in[14];
    const float* b4     = (const float*)d_in[15];

    const int N = in_sizes[0] / 128;
    const int E = in_sizes[1] / 2;
    const int* row = ei;
    const int* col = ei + E;

    size_t off = 0;
    auto alloc = [&](size_t bytes) -> void* {
        void* p = (char*)d_ws + off;
        off += (bytes + 255) & ~(size_t)255;
        return p;
    };
    int*   deg    = (int*)alloc((size_t)N * 4);
    int*   rp     = (int*)alloc((size_t)(N + 1) * 4);
    int*   cursor = (int*)alloc((size_t)N * 4);
    int*   colS   = (int*)alloc((size_t)E * 4);
    int*   bsum   = (int*)alloc((size_t)64 * 4);
    float* dinv   = (float*)alloc((size_t)N * 4);
    float* cinv   = (float*)alloc((size_t)N * 4);
    unsigned short* Wt0 = (unsigned short*)alloc((size_t)128 * 128 * 2);
    unsigned short* Wt1 = (unsigned short*)alloc((size_t)256 * 256 * 2);
    unsigned short* Wt2 = (unsigned short*)alloc((size_t)256 * 512 * 2);
    unsigned short* Wt3 = (unsigned short*)alloc((size_t)256 * 256 * 2);
    unsigned short* Wt4p= (unsigned short*)alloc((size_t)256 * 256 * 2);
    float* biasP  = (float*)alloc((size_t)256 * 4);
    unsigned short* Xb  = (unsigned short*)alloc((size_t)N * 128 * 2);
    unsigned short* Gb  = (unsigned short*)alloc((size_t)N * 256 * 2);
    unsigned short* Pb  = (unsigned short*)alloc((size_t)N * 256 * 2);
    unsigned short* Ab  = (unsigned short*)alloc((size_t)N * 256 * 2);
    unsigned short* Hb  = Xb;  // alias: Xb only read by L0 agg before Hb written
    (void)ws_size;

    // ---- CSR build ----
    const int SB = (N + 2047) / 2048;
    zero_int_kernel<<<(N + 255) / 256, 256, 0, stream>>>(deg, N);
    count_deg_kernel<<<(E + 255) / 256, 256, 0, stream>>>(row, deg, E);
    scan_p1_kernel<<<SB, 1024, 0, stream>>>(deg, rp, bsum, N);
    scan_p2_kernel<<<1, 64, 0, stream>>>(bsum, SB);
    scan_p3_kernel<<<SB, 1024, 0, stream>>>(deg, rp, cursor, bsum, dinv, cinv, N);
    fill_csr_kernel<<<(E + 255) / 256, 256, 0, stream>>>(row, col, cursor, colS, E);

    // ---- prep ----
    f32_to_f16_kernel<<<(N * 32 + 255) / 256, 256, 0, stream>>>(x, Xb, N * 32);
    prep_w_kernel<<<(128 * 128 + 255) / 256, 256, 0, stream>>>(W0, 128, nullptr, 0, 128, 128, Wt0);
    prep_w_kernel<<<(256 * 256 + 255) / 256, 256, 0, stream>>>(W1, 128, R1, 128, 256, 256, Wt1);
    prep_w_kernel<<<(256 * 512 + 255) / 256, 256, 0, stream>>>(W2, 256, R2, 256, 256, 256, Wt2);
    prep_w_kernel<<<(256 * 256 + 255) / 256, 256, 0, stream>>>(W3, 256, nullptr, 0, 256, 256, Wt3);
    prep_w2_kernel<<<(256 * 256) / 256, 256, 0, stream>>>(W4, R4, Wt4p);
    prep_biasP_kernel<<<1, 256, 0, stream>>>(b4, biasP);

    dim3 aggGrid((N + 3) / 4);
    dim3 g1((N + 127) / 128, 1);

    // ---- L0 (GCN): Hb = f16( x + a0*(gcn_agg(x)@W0 + b0) ) ----
    agg_f16_kernel<128, true, 0><<<aggGrid, 256, 0, stream>>>(
        Xb, 128, rp, colS, dinv, dinv, Ab, 128, nullptr, 0, N);
    mfma_gemm_kernel<128, 2, false, false, true><<<g1, 256, 0, stream>>>(
        Ab, 128, 128, nullptr, 0, 0, Wt0, b0, x, 128, alpha, 0,
        nullptr, Hb, 128, N, 128);

    // ---- L1 (SAGE 128->256): Gb = relu([mean(Hb)|Hb]@[W1;R1]+b1) ----
    agg_f16_kernel<128, false, 0><<<aggGrid, 256, 0, stream>>>(
        Hb, 128, rp, colS, nullptr, cinv, Ab, 128, nullptr, 0, N);
    mfma_gemm_kernel<256, 1, false, false, true><<<g1, 512, 0, stream>>>(
        Ab, 128, 128, Hb, 128, 128, Wt1, b1, nullptr, 0, nullptr, 0,
        nullptr, Gb, 256, N, 256);

    // ---- L2 (SAGE 256->256): Pb = relu([mean(Gb)|Gb]@[W2;R2]+b2) ----
    agg_f16_kernel<256, false, 0><<<aggGrid, 256, 0, stream>>>(
        Gb, 256, rp, colS, nullptr, cinv, Ab, 256, nullptr, 0, N);
    mfma_gemm_kernel<256, 1, false, false, true><<<g1, 512, 0, stream>>>(
        Ab, 256, 256, Gb, 256, 256, Wt2, b2, nullptr, 0, nullptr, 0,
        nullptr, Pb, 256, N, 256);

    // ---- L3 (GCN): Gb = Pb + a3*(gcn_agg(Pb)@W3 + b3) ----
    agg_f16_kernel<256, true, 0><<<aggGrid, 256, 0, stream>>>(
        Pb, 256, rp, colS, dinv, dinv, Ab, 256, nullptr, 0, N);
    mfma_gemm_kernel<256, 2, true, false, true><<<g1, 512, 0, stream>>>(
        Ab, 256, 256, nullptr, 0, 0, Wt3, b3, Pb, 256, alpha, 3,
        nullptr, Gb, 256, N, 256);

    // ---- L4 (SAGE 256->112), commuted: T = Gb@W4 (f16), U = Gb@R4+b4 ->
    //      d_out; then d_out += cinv * A * T ----
    mfma_gemm_kernel<256, 3, false, false, false><<<g1, 512, 0, stream>>>(
        Gb, 256, 256, nullptr, 0, 0, Wt4p, biasP, nullptr, 112, nullptr, 0,
        (float*)d_out, Ab, 128, N, 224);
    agg_f16_kernel<128, false, 1><<<aggGrid, 256, 0, stream>>>(
        Ab, 128, rp, colS, nullptr, cinv, nullptr, 0, (float*)d_out, 112, N);
}